// Round 1
// baseline (223.601 us; speedup 1.0000x reference)
//
#include <hip/hip_runtime.h>

// ---------------------------------------------------------------------------
// Block-sparse linear  y = x @ W^T + bias  on MI355X (gfx950)
// Round 3: 2-phase double-buffered pipeline (stage k+1 issued BEFORE compute
// of k, ONE barrier per k-step instead of two full-drain barriers), NT=256
// with 8 waves (halves B-tile L2 traffic, halves barriers/FLOP), merged
// rb-pair k-loop (no pipeline bubble at the half boundary), XCD-aware
// workgroup swizzle (each XCD keeps its 2 x-panels = 4MB in private L2),
// CSR build fused into the convert kernel (one fewer serialized launch).
// Round-2 result for reference: bsl_main 58us, MfmaUtil 22%, VALUBusy 14%,
// bank conflicts 0 -> latency/barrier-bound, not BW-bound.
// ---------------------------------------------------------------------------

typedef __attribute__((ext_vector_type(8))) short bf16x8;   // MFMA A/B frag
typedef __attribute__((ext_vector_type(8))) unsigned short u16x8;
typedef __attribute__((ext_vector_type(4))) float f32x4;     // MFMA C/D frag

#define N_ROWS 4096
#define IN_DIM 4096
#define OUT_DIM 4096
#define BS 64
#define K_BLOCKS 1024
#define NT 256            // rows per workgroup tile (8 waves x 32 rows)
#define PK_STRIDE 256     // max blocks per row-block we store (>> realistic max ~35)

// fp32 -> bf16 round-to-nearest-even
__device__ static inline unsigned short f2bf(float f) {
    unsigned u = __float_as_uint(f);
    u += 0x7FFFu + ((u >> 16) & 1u);
    return (unsigned short)(u >> 16);
}

__device__ static inline void async_copy16(const void* g, void* l) {
    __builtin_amdgcn_global_load_lds(
        (const __attribute__((address_space(1))) void*)g,
        (__attribute__((address_space(3))) void*)l, 16, 0, 0);
}

// --- prep: convert x (16M f32) + blocks (4M f32) to bf16, AND build CSR ----
// Blocks 0..10239 convert (each thread 8 floats); block 10240 builds the
// CSR + balanced pair schedule (independent work, runs concurrently).
__global__ void bsl_prep(const float* __restrict__ x,
                         const float* __restrict__ blocks,
                         unsigned short* __restrict__ xb,
                         unsigned short* __restrict__ bb,
                         const int* __restrict__ row_idx,
                         const int* __restrict__ col_idx,
                         int* __restrict__ counts,
                         int* __restrict__ sched,
                         int* __restrict__ csr_pk) {
    if (blockIdx.x == 10240) {
        // ---- CSR + schedule with 256 threads ----
        __shared__ int cnt_s[64];
        __shared__ int sorted_s[64];
        const int t = threadIdx.x;
        if (t < 64) cnt_s[t] = 0;
        __syncthreads();
#pragma unroll
        for (int i = 0; i < 4; ++i) {
            const int k = t + i * 256;           // 0..1023
            const int r = row_idx[k];
            const int rank = atomicAdd(&cnt_s[r], 1);
            if (rank < PK_STRIDE) csr_pk[r * PK_STRIDE + rank] = (k << 6) | col_idx[k];
        }
        __syncthreads();
        if (t < 64) {
            const int mc = cnt_s[t];
            counts[t] = mc;
            int pos = 0;
            for (int j = 0; j < 64; ++j) {
                const int cj = cnt_s[j];
                pos += (cj > mc || (cj == mc && j < t)) ? 1 : 0;
            }
            sorted_s[pos] = t;
        }
        __syncthreads();
        if (t < 32) {
            sched[t * 2]     = sorted_s[t];
            sched[t * 2 + 1] = sorted_s[63 - t];
        }
        return;
    }
    // ---- convert ----
    long t = (long)blockIdx.x * 256 + threadIdx.x;   // 0 .. 2621439 (8 floats each)
    const float4* src;
    unsigned short* dst;
    long off4;
    if (t < 2097152) {            // x region
        src = (const float4*)x;  dst = xb;  off4 = t * 2;
    } else {                      // blocks region
        src = (const float4*)blocks;  dst = bb;  off4 = (t - 2097152) * 2;
    }
    float4 a = src[off4];
    float4 b = src[off4 + 1];
    u16x8 v;
    v[0] = f2bf(a.x); v[1] = f2bf(a.y); v[2] = f2bf(a.z); v[3] = f2bf(a.w);
    v[4] = f2bf(b.x); v[5] = f2bf(b.y); v[6] = f2bf(b.z); v[7] = f2bf(b.w);
    *(u16x8*)(dst + off4 * 4) = v;
}

// --- main: per (n-tile, rb-pair) MFMA accumulation, 2-phase dbuf pipeline --
// LDS 16B-slot swizzle: phys slot s in row r holds col-chunk s^(r&7); staging
// pre-swizzles the GLOBAL source address (global_load_lds dest must be linear,
// base + lane*16); read side xors with m&7 (all fragment rows have
// row&7 == m&7). Verified 0 bank conflicts in rounds 1-2.
__global__ __launch_bounds__(512, 4) void bsl_main(
    const unsigned short* __restrict__ xb,   // [4096][4096] bf16
    const unsigned short* __restrict__ blk,  // [1024][64][64] bf16
    const float* __restrict__ bias,
    const int* __restrict__ counts,
    const int* __restrict__ sched,
    const int* __restrict__ csr_pk,
    float* __restrict__ y) {
    __shared__ unsigned short a_lds[2][NT * 64];   // 2 x 32 KB
    __shared__ unsigned short b_lds[2][64 * 64];   // 2 x  8 KB   (80 KB total)

    const int tid = threadIdx.x;
    const int w = tid >> 6;        // wave 0..7 -> rows [w*32, w*32+32)
    const int l = tid & 63;
    const int m = l & 15;          // MFMA lane coord
    const int q = l >> 4;          // quad

    // XCD-aware decode: 512 wgs, consecutive ids round-robin XCDs; XCD x owns
    // nt in {2x, 2x+1} for ALL 32 pairs -> its 2 x-panels (4MB bf16) stay in
    // its private 4MB L2.
    const int bid = blockIdx.x;
    const int xcd = bid & 7;
    const int idx = bid >> 3;              // 0..63
    const int nt  = xcd * 2 + (idx & 1);   // 0..15
    const int p   = idx >> 1;              // 0..31
    const int n0  = nt * NT;

    const int rb0  = sched[p * 2];
    const int rb1  = sched[p * 2 + 1];
    const int cnt0 = counts[rb0];
    const int cnt1 = counts[rb1];
    const int total = cnt0 + cnt1;

    // staging lane constants (pre-swizzled global source)
    const int srow = l >> 3;                    // 0..7
    const int scc  = (l & 7) ^ srow;            // swizzled col-chunk
    const int scol = scc * 8;
    const int xorv = m & 7;                     // read-side swizzle

    const unsigned short* xb_base = xb + (size_t)(n0 + srow) * IN_DIM + scol;
    const unsigned short* bb_base = blk + (size_t)(w * 8 + srow) * 64 + scol;

    f32x4 acc[2][4];
#pragma unroll
    for (int r = 0; r < 2; ++r)
#pragma unroll
        for (int c = 0; c < 4; ++c) acc[r][c] = (f32x4){0.f, 0.f, 0.f, 0.f};

    auto fetch_pk = [&](int i) -> int {
        return (i < cnt0) ? csr_pk[rb0 * PK_STRIDE + i]
                          : csr_pk[rb1 * PK_STRIDE + (i - cnt0)];
    };

    // stage A tile (256x64 = 32 chunks of 1KB; wave w: chunks i*8+w) and
    // B tile (64x64 = 8 chunks; wave w: chunk w) into buffer `buf`.
    auto stage = [&](int buf, int k, int ci) {
        const unsigned short* xrow = xb_base + ci * 64;
#pragma unroll
        for (int i = 0; i < 4; ++i) {
            const int ch = i * 8 + w;
            async_copy16(xrow + (size_t)(ch * 8) * IN_DIM, &a_lds[buf][ch * 512]);
        }
        async_copy16(bb_base + (size_t)k * 4096, &b_lds[buf][w * 512]);
    };

    // epilogue: C/D layout col=lane&15, row=q*4+e (harness-verified in r1/r2)
    auto epilogue = [&](int rb) {
        const int colbase = rb * 64;
#pragma unroll
        for (int c = 0; c < 4; ++c) {
            const float bv = bias[colbase + c * 16 + m];
#pragma unroll
            for (int r = 0; r < 2; ++r) {
                const int rowb = n0 + w * 32 + r * 16 + q * 4;
#pragma unroll
                for (int e = 0; e < 4; ++e) {
                    y[(size_t)(rowb + e) * OUT_DIM + colbase + c * 16 + m] =
                        acc[r][c][e] + bv;
                }
            }
        }
    };

    // ---- 2-phase pipeline: STAGE(next) issued BEFORE compute(current);
    //      ONE vmcnt-draining barrier per k-step.
    int cur = 0;
    if (total > 0) {
        const int pk = fetch_pk(0);
        stage(0, pk >> 6, pk & 63);
    }
    if (cnt0 == 0) epilogue(rb0);          // bias-only row-block (acc == 0)
    __syncthreads();                       // buffer 0 ready

    for (int i = 0; i < total; ++i) {
        if (i + 1 < total) {               // prefetch next tile into buf^1
            const int pk = fetch_pk(i + 1);
            stage(cur ^ 1, pk >> 6, pk & 63);
        }

        // compute current tile from buf[cur]
#pragma unroll
        for (int s = 0; s < 2; ++s) {
            bf16x8 af[2], bfr[4];
            const int cc = (s * 4 + q) ^ xorv;
#pragma unroll
            for (int r = 0; r < 2; ++r) {
                const int row = w * 32 + r * 16 + m;
                af[r] = *(const bf16x8*)(&a_lds[cur][row * 64 + cc * 8]);
            }
#pragma unroll
            for (int c = 0; c < 4; ++c) {
                const int row = c * 16 + m;
                bfr[c] = *(const bf16x8*)(&b_lds[cur][row * 64 + cc * 8]);
            }
#pragma unroll
            for (int r = 0; r < 2; ++r)
#pragma unroll
                for (int c = 0; c < 4; ++c)
                    acc[r][c] = __builtin_amdgcn_mfma_f32_16x16x32_bf16(
                        af[r], bfr[c], acc[r][c], 0, 0, 0);
        }

        if (i == cnt0 - 1) {               // rb0 done: write while rb1's first
            epilogue(rb0);                 // stage is still in flight
#pragma unroll
            for (int r = 0; r < 2; ++r)
#pragma unroll
                for (int c = 0; c < 4; ++c) acc[r][c] = (f32x4){0.f, 0.f, 0.f, 0.f};
        }

        __syncthreads();                   // drains vmcnt -> buf^1 ready,
        cur ^= 1;                          // and buf[cur] reads all done
    }

    epilogue(rb1);                         // bias-only if cnt1 == 0
}

// ---------------------------------------------------------------------------
extern "C" void kernel_launch(void* const* d_in, const int* in_sizes, int n_in,
                              void* d_out, int out_size, void* d_ws, size_t ws_size,
                              hipStream_t stream) {
    const float* x      = (const float*)d_in[0];
    const float* blocks = (const float*)d_in[1];
    const float* bias   = (const float*)d_in[2];
    const int* row_idx  = (const int*)d_in[3];
    const int* col_idx  = (const int*)d_in[4];
    float* y = (float*)d_out;

    // ws layout: x_bf16 (32MB) | blocks_bf16 (8MB) | counts(64) | sched(64) |
    //            pad | csr_pk (64*PK_STRIDE ints)
    const size_t base = 41943040u;   // 40 MB
    unsigned short* xb = (unsigned short*)d_ws;
    unsigned short* bb = xb + (size_t)N_ROWS * IN_DIM;
    int* counts = (int*)((char*)d_ws + base);
    int* sched  = counts + 64;
    int* csr_pk = (int*)((char*)d_ws + base + 1024);
    if (ws_size < base + 1024 + (size_t)64 * PK_STRIDE * 4) return;

    hipLaunchKernelGGL(bsl_prep, dim3(10241), dim3(256), 0, stream,
                       x, blocks, xb, bb, row_idx, col_idx, counts, sched, csr_pk);
    hipLaunchKernelGGL(bsl_main, dim3(512), dim3(512), 0, stream,
                       xb, bb, bias, counts, sched, csr_pk, y);
}

// Round 2
// 198.607 us; speedup vs baseline: 1.1258x; 1.1258x over previous
//
#include <hip/hip_runtime.h>

// ---------------------------------------------------------------------------
// Block-sparse linear  y = x @ W^T + bias  on MI355X (gfx950)
// Round 4: revert to round-2 geometry (NT=128, 256 thr, 4 waves, acc[2][4],
// 24 KB LDS) -- round 3 showed fat 512-thread wgs with 80KB LDS collapse to
// 2 wgs/CU and lose the multi-workgroup latency hiding (58->95us).
// New here: (a) k-split double-buffer -- each block's K=64 done as two k=32
// half-steps, so TWO 12KB buffers fit in the same 24KB and we get a 2-phase
// prefetch pipeline (stage t+1 issued before compute t, ONE barrier/step)
// at UNCHANGED occupancy; (b) un-paired LPT schedule: one rb per wg, grid
// 32x64=2048 wgs dispatched heavy-first, launch_bounds(256,6) -> up to 6
// resident wgs/CU (6 independent barrier groups) + queue for load balance.
// Round-2 counters for reference: 58us, MfmaUtil 22%, VALUBusy 14%, 0 bank
// conflicts, Occ 32% -> latency/barrier-bound.
// ---------------------------------------------------------------------------

typedef __attribute__((ext_vector_type(8))) short bf16x8;   // MFMA A/B frag
typedef __attribute__((ext_vector_type(8))) unsigned short u16x8;
typedef __attribute__((ext_vector_type(4))) float f32x4;     // MFMA C/D frag

#define N_ROWS 4096
#define IN_DIM 4096
#define OUT_DIM 4096
#define BS 64
#define K_BLOCKS 1024
#define NT 128            // rows per workgroup tile (4 waves x 32 rows)
#define PK_STRIDE 256     // max blocks per row-block we store (>> realistic max ~35)

// fp32 -> bf16 round-to-nearest-even
__device__ static inline unsigned short f2bf(float f) {
    unsigned u = __float_as_uint(f);
    u += 0x7FFFu + ((u >> 16) & 1u);
    return (unsigned short)(u >> 16);
}

__device__ static inline void async_copy16(const void* g, void* l) {
    __builtin_amdgcn_global_load_lds(
        (const __attribute__((address_space(1))) void*)g,
        (__attribute__((address_space(3))) void*)l, 16, 0, 0);
}

// --- prep: convert x (16M f32) + blocks (4M f32) to bf16, AND build CSR ----
// Blocks 0..10239 convert (each thread 8 floats); block 10240 builds the
// CSR + descending-count schedule (independent work, runs concurrently).
__global__ void bsl_prep(const float* __restrict__ x,
                         const float* __restrict__ blocks,
                         unsigned short* __restrict__ xb,
                         unsigned short* __restrict__ bb,
                         const int* __restrict__ row_idx,
                         const int* __restrict__ col_idx,
                         int* __restrict__ counts,
                         int* __restrict__ sched,
                         int* __restrict__ csr_pk) {
    if (blockIdx.x == 10240) {
        // ---- CSR + LPT schedule with 256 threads ----
        __shared__ int cnt_s[64];
        __shared__ int sorted_s[64];
        const int t = threadIdx.x;
        if (t < 64) cnt_s[t] = 0;
        __syncthreads();
#pragma unroll
        for (int i = 0; i < 4; ++i) {
            const int k = t + i * 256;           // 0..1023
            const int r = row_idx[k];
            const int rank = atomicAdd(&cnt_s[r], 1);
            if (rank < PK_STRIDE) csr_pk[r * PK_STRIDE + rank] = (k << 6) | col_idx[k];
        }
        __syncthreads();
        if (t < 64) {
            const int mc = cnt_s[t];
            counts[t] = mc;
            int pos = 0;
            for (int j = 0; j < 64; ++j) {
                const int cj = cnt_s[j];
                pos += (cj > mc || (cj == mc && j < t)) ? 1 : 0;
            }
            sorted_s[pos] = t;                   // descending by count
        }
        __syncthreads();
        if (t < 64) sched[t] = sorted_s[t];      // heavy row-blocks first (LPT)
        return;
    }
    // ---- convert ----
    long t = (long)blockIdx.x * 256 + threadIdx.x;   // 0 .. 2621439 (8 floats each)
    const float4* src;
    unsigned short* dst;
    long off4;
    if (t < 2097152) {            // x region
        src = (const float4*)x;  dst = xb;  off4 = t * 2;
    } else {                      // blocks region
        src = (const float4*)blocks;  dst = bb;  off4 = (t - 2097152) * 2;
    }
    float4 a = src[off4];
    float4 b = src[off4 + 1];
    u16x8 v;
    v[0] = f2bf(a.x); v[1] = f2bf(a.y); v[2] = f2bf(a.z); v[3] = f2bf(a.w);
    v[4] = f2bf(b.x); v[5] = f2bf(b.y); v[6] = f2bf(b.z); v[7] = f2bf(b.w);
    *(u16x8*)(dst + off4 * 4) = v;
}

// --- main: per (n-tile, rb) MFMA accumulation, k-split 2-phase pipeline ----
// Half-step = one (block, k-half) pair: A half-tile 128x32 bf16 (8KB) +
// B half-tile 64x32 (4KB). LDS swizzle (16B slots, 4 per row): phys chunk
// pc = logical chunk ^ (row & 3). Staging pre-swizzles the GLOBAL source
// column (global_load_lds dest must be linear, base + lane*16); read side
// xors with m&3 (every fragment row has row&3 == m&3). Bank check: read
// lanes spread 8-per-4-bank-group uniformly -> conflict-free.
__global__ __launch_bounds__(256, 6) void bsl_main(
    const unsigned short* __restrict__ xb,   // [4096][4096] bf16
    const unsigned short* __restrict__ blk,  // [1024][64][64] bf16
    const float* __restrict__ bias,
    const int* __restrict__ counts,
    const int* __restrict__ sched,
    const int* __restrict__ csr_pk,
    float* __restrict__ y) {
    __shared__ unsigned short a_lds[2][NT * 32];   // 2 x 8 KB
    __shared__ unsigned short b_lds[2][64 * 32];   // 2 x 4 KB   (24 KB total)

    const int tid = threadIdx.x;
    const int w = tid >> 6;        // wave 0..3 -> rows [w*32, w*32+32)
    const int l = tid & 63;
    const int m = l & 15;          // MFMA lane coord
    const int q = l >> 4;          // quad -> k-chunk within the 32-k half

    const int nt = blockIdx.x;     // 32 n-tiles of 128 rows
    const int n0 = nt * NT;
    const int rb = sched[blockIdx.y];   // heavy rbs dispatched first
    const int cnt = counts[rb];
    const int tsteps = cnt * 2;

    // staging lane constants (pre-swizzled global source)
    const int srow4 = l >> 2;                   // 0..15 row within 16-row chunk
    const int scc4  = (l & 3) ^ (srow4 & 3);    // swizzled 16B col-chunk (0..3)
    const unsigned short* xb_lane =
        xb + (size_t)(n0 + srow4) * IN_DIM + scc4 * 8;
    const unsigned short* bb_lane =
        blk + (size_t)(w * 16 + srow4) * 64 + scc4 * 8;

    // read-side swizzle + hoisted LDS element offsets
    const int pc = q ^ (m & 3);                 // phys chunk for this lane
    int aoff[2], boff[4];
#pragma unroll
    for (int r = 0; r < 2; ++r) aoff[r] = (w * 32 + r * 16 + m) * 32 + pc * 8;
#pragma unroll
    for (int c = 0; c < 4; ++c) boff[c] = (c * 16 + m) * 32 + pc * 8;

    f32x4 acc[2][4];
#pragma unroll
    for (int r = 0; r < 2; ++r)
#pragma unroll
        for (int c = 0; c < 4; ++c) acc[r][c] = (f32x4){0.f, 0.f, 0.f, 0.f};

    // stage half-step t into buffer `buf`: j = t>>1 (block), s = t&1 (k-half)
    auto stage = [&](int buf, int t) {
        const int j  = t >> 1;
        const int s  = t & 1;
        const int pk = csr_pk[rb * PK_STRIDE + j];
        const int k  = pk >> 6;
        const int ci = pk & 63;
        // A: 8 chunks of 1KB (16 rows x 64B); wave w stages chunks {w, w+4}
        const unsigned short* xs = xb_lane + ci * 64 + s * 32;
#pragma unroll
        for (int i = 0; i < 2; ++i) {
            const int ch = i * 4 + w;
            async_copy16(xs + (size_t)(ch * 16) * IN_DIM, &a_lds[buf][ch * 512]);
        }
        // B: 4 chunks; wave w stages chunk w (rows w*16..w*16+15)
        async_copy16(bb_lane + (size_t)k * 4096 + s * 32, &b_lds[buf][w * 512]);
    };

    // ---- 2-phase pipeline: STAGE(t+1) issued BEFORE compute(t);
    //      ONE vmcnt+lgkm-draining barrier per half-step.
    int cur = 0;
    if (tsteps > 0) stage(0, 0);
    __syncthreads();

    for (int t = 0; t < tsteps; ++t) {
        if (t + 1 < tsteps) stage(cur ^ 1, t + 1);

        bf16x8 af[2], bfr[4];
#pragma unroll
        for (int r = 0; r < 2; ++r)
            af[r] = *(const bf16x8*)(&a_lds[cur][aoff[r]]);
#pragma unroll
        for (int c = 0; c < 4; ++c)
            bfr[c] = *(const bf16x8*)(&b_lds[cur][boff[c]]);
#pragma unroll
        for (int r = 0; r < 2; ++r)
#pragma unroll
            for (int c = 0; c < 4; ++c)
                acc[r][c] = __builtin_amdgcn_mfma_f32_16x16x32_bf16(
                    af[r], bfr[c], acc[r][c], 0, 0, 0);

        __syncthreads();               // buf^1 loads landed; buf[cur] reads done
        cur ^= 1;
    }

    // epilogue: C/D layout col=lane&15, row=q*4+e (harness-verified r1-r3)
    const int colbase = rb * 64;
#pragma unroll
    for (int c = 0; c < 4; ++c) {
        const float bv = bias[colbase + c * 16 + m];
#pragma unroll
        for (int r = 0; r < 2; ++r) {
            const int rowb = n0 + w * 32 + r * 16 + q * 4;
#pragma unroll
            for (int e = 0; e < 4; ++e) {
                y[(size_t)(rowb + e) * OUT_DIM + colbase + c * 16 + m] =
                    acc[r][c][e] + bv;
            }
        }
    }
}

// ---------------------------------------------------------------------------
extern "C" void kernel_launch(void* const* d_in, const int* in_sizes, int n_in,
                              void* d_out, int out_size, void* d_ws, size_t ws_size,
                              hipStream_t stream) {
    const float* x      = (const float*)d_in[0];
    const float* blocks = (const float*)d_in[1];
    const float* bias   = (const float*)d_in[2];
    const int* row_idx  = (const int*)d_in[3];
    const int* col_idx  = (const int*)d_in[4];
    float* y = (float*)d_out;

    // ws layout: x_bf16 (32MB) | blocks_bf16 (8MB) | counts(64) | sched(64) |
    //            pad | csr_pk (64*PK_STRIDE ints)
    const size_t base = 41943040u;   // 40 MB
    unsigned short* xb = (unsigned short*)d_ws;
    unsigned short* bb = xb + (size_t)N_ROWS * IN_DIM;
    int* counts = (int*)((char*)d_ws + base);
    int* sched  = counts + 64;
    int* csr_pk = (int*)((char*)d_ws + base + 1024);
    if (ws_size < base + 1024 + (size_t)64 * PK_STRIDE * 4) return;

    hipLaunchKernelGGL(bsl_prep, dim3(10241), dim3(256), 0, stream,
                       x, blocks, xb, bb, row_idx, col_idx, counts, sched, csr_pk);
    hipLaunchKernelGGL(bsl_main, dim3(32, 64), dim3(256), 0, stream,
                       xb, bb, bias, counts, sched, csr_pk, y);
}